// Round 1
// baseline (259.245 us; speedup 1.0000x reference)
//
#include <hip/hip_runtime.h>
#include <math.h>

#define NPV 3072
#define LDP 3073
#define EPSF 1e-8f
#define NSEG 16
#define SEGROWS (NPV / NSEG)

__device__ __forceinline__ void ins3(float v, float& a, float& b, float& c) {
    if (v > a) { c = b; b = a; a = v; }
    else if (v > b) { c = b; b = v; }
    else if (v > c) { c = v; }
}

// One block per row: top-3 of the row, write 3rd-largest to tr[i].
__global__ __launch_bounds__(256) void k_row_top3(const float* __restrict__ P, float* __restrict__ tr)
{
    int i = blockIdx.x;
    int t = threadIdx.x;
    const float* row = P + (size_t)i * LDP;
    float a = -1e30f, b = -1e30f, c = -1e30f;
    for (int j = t; j < NPV; j += 256) ins3(row[j], a, b, c);
    __shared__ float sa[256], sb[256], sc[256];
    sa[t] = a; sb[t] = b; sc[t] = c;
    __syncthreads();
    for (int s = 128; s > 0; s >>= 1) {
        if (t < s) {
            float xa = sa[t + s], xb = sb[t + s], xc = sc[t + s];
            a = sa[t]; b = sb[t]; c = sc[t];
            ins3(xa, a, b, c); ins3(xb, a, b, c); ins3(xc, a, b, c);
            sa[t] = a; sb[t] = b; sc[t] = c;
        }
        __syncthreads();
    }
    if (t == 0) tr[i] = sc[0];
}

// Partial column top-3 over a row segment. grid (NPV/256, NSEG).
__global__ __launch_bounds__(256) void k_col_top3_part(const float* __restrict__ P, float* __restrict__ part)
{
    int j = blockIdx.x * 256 + threadIdx.x;
    int i0 = blockIdx.y * SEGROWS;
    float a = -1e30f, b = -1e30f, c = -1e30f;
    for (int i = i0; i < i0 + SEGROWS; ++i) ins3(P[(size_t)i * LDP + j], a, b, c);
    size_t o = ((size_t)blockIdx.y * NPV + j) * 3;
    part[o] = a; part[o + 1] = b; part[o + 2] = c;
}

__global__ __launch_bounds__(256) void k_col_merge(const float* __restrict__ part, float* __restrict__ tc)
{
    int j = blockIdx.x * 256 + threadIdx.x;
    float a = -1e30f, b = -1e30f, c = -1e30f;
    for (int s = 0; s < NSEG; ++s) {
        size_t o = ((size_t)s * NPV + j) * 3;
        ins3(part[o], a, b, c); ins3(part[o + 1], a, b, c); ins3(part[o + 2], a, b, c);
    }
    tc[j] = c;
}

// One block per row: collect masked entries (<=3 barring ties; 8 slots for safety),
// sort by j (deterministic, matches jnp ascending-j summation for w1).
__global__ __launch_bounds__(256) void k_collect(const float* __restrict__ P,
        const float* __restrict__ tr, const float* __restrict__ tc,
        int* __restrict__ rowcnt, int* __restrict__ rowj,
        float* __restrict__ roww, float* __restrict__ w1)
{
    int i = blockIdx.x, t = threadIdx.x;
    __shared__ int cnt;
    __shared__ int js[8];
    __shared__ float vsv[8];
    if (t == 0) cnt = 0;
    __syncthreads();
    float tri = tr[i];
    const float* row = P + (size_t)i * LDP;
    for (int j = t; j < NPV; j += 256) {
        float v = row[j];
        if (v >= tri && v >= tc[j] && v > 0.01f) {
            int p = atomicAdd(&cnt, 1);
            if (p < 8) { js[p] = j; vsv[p] = v; }
        }
    }
    __syncthreads();
    if (t == 0) {
        int n = cnt < 8 ? cnt : 8;
        for (int x = 1; x < n; ++x) {
            int jx = js[x]; float vx = vsv[x]; int y = x - 1;
            while (y >= 0 && js[y] > jx) { js[y + 1] = js[y]; vsv[y + 1] = vsv[y]; --y; }
            js[y + 1] = jx; vsv[y + 1] = vx;
        }
        float s = 0.f;
        for (int x = 0; x < n; ++x) { rowj[i * 8 + x] = js[x]; roww[i * 8 + x] = vsv[x]; s += vsv[x]; }
        rowcnt[i] = n;
        w1[i] = s;
    }
}

__device__ float block_reduce(float v, float* red) {
    int t = threadIdx.x;
    red[t] = v;
    __syncthreads();
    for (int s = 128; s > 0; s >>= 1) {
        if (t < s) red[t] += red[t + s];
        __syncthreads();
    }
    float r = red[0];
    __syncthreads();
    return r;
}

__device__ void mat3mul(const float* A, const float* B, float* C) {
    for (int r = 0; r < 3; ++r)
        for (int c = 0; c < 3; ++c)
            C[r * 3 + c] = A[r * 3] * B[c] + A[r * 3 + 1] * B[3 + c] + A[r * 3 + 2] * B[6 + c];
}

__device__ float det3(const float* M) {
    return M[0] * (M[4] * M[8] - M[5] * M[7])
         - M[1] * (M[3] * M[8] - M[5] * M[6])
         + M[2] * (M[3] * M[7] - M[4] * M[6]);
}

__device__ void powiter3(const float* M, float* v) {
    v[0] = v[1] = v[2] = 0.57735026918962584f;  // 1/sqrt(3)
    for (int it = 0; it < 50; ++it) {
        float y0 = M[0] * v[0] + M[1] * v[1] + M[2] * v[2];
        float y1 = M[3] * v[0] + M[4] * v[1] + M[5] * v[2];
        float y2 = M[6] * v[0] + M[7] * v[1] + M[8] * v[2];
        float n = sqrtf(y0 * y0 + y1 * y1 + y2 * y2) + EPSF;
        v[0] = y0 / n; v[1] = y1 / n; v[2] = y2 / n;
    }
}

__global__ __launch_bounds__(256) void k_final(const float* __restrict__ Kmat,
        const int* __restrict__ rowcnt, const int* __restrict__ rowj,
        const float* __restrict__ roww, const float* __restrict__ w1g,
        float* __restrict__ out)
{
    __shared__ float sW2[NPV];
    __shared__ float red[256];
    __shared__ float sKi[9];
    __shared__ float sPar[6];   // c1x,c1y,s1, c2x,c2y,s2
    __shared__ float sMs[81];
    __shared__ float sV9[9];
    __shared__ float sMred[4 * 45];
    int t = threadIdx.x;

    if (t == 0) {
        float k00 = Kmat[0], k01 = Kmat[1], k02 = Kmat[2];
        float k10 = Kmat[3], k11 = Kmat[4], k12 = Kmat[5];
        float k20 = Kmat[6], k21 = Kmat[7], k22 = Kmat[8];
        float det = k00 * (k11 * k22 - k12 * k21) - k01 * (k10 * k22 - k12 * k20) + k02 * (k10 * k21 - k11 * k20);
        float id = 1.0f / det;
        sKi[0] = (k11 * k22 - k12 * k21) * id; sKi[1] = (k02 * k21 - k01 * k22) * id; sKi[2] = (k01 * k12 - k02 * k11) * id;
        sKi[3] = (k12 * k20 - k10 * k22) * id; sKi[4] = (k00 * k22 - k02 * k20) * id; sKi[5] = (k02 * k10 - k00 * k12) * id;
        sKi[6] = (k10 * k21 - k11 * k20) * id; sKi[7] = (k01 * k20 - k00 * k21) * id; sKi[8] = (k00 * k11 - k01 * k10) * id;
    }
    for (int j = t; j < NPV; j += 256) sW2[j] = 0.f;
    __syncthreads();

    // w2 (column sums of sparse weights). ulp-level atomic ordering noise only.
    for (int i = t; i < NPV; i += 256) {
        int n = rowcnt[i];
        for (int x = 0; x < n; ++x) atomicAdd(&sW2[rowj[i * 8 + x]], roww[i * 8 + x]);
    }
    __syncthreads();

    auto PX = [&](int i) -> float {
        float x = (float)(i & 63), y = (float)(i >> 6);
        return sKi[0] * x + sKi[1] * y + sKi[2];
    };
    auto PY = [&](int i) -> float {
        float x = (float)(i & 63), y = (float)(i >> 6);
        return sKi[3] * x + sKi[4] * y + sKi[5];
    };

    // Hartley normalization for both point sets (same pts, different weights).
    for (int set = 0; set < 2; ++set) {
        float sw = 0.f, sx = 0.f, sy = 0.f;
        for (int i = t; i < NPV; i += 256) {
            float w = set ? sW2[i] : w1g[i];
            sw += w; sx += w * PX(i); sy += w * PY(i);
        }
        sw = block_reduce(sw, red);
        sx = block_reduce(sx, red);
        sy = block_reduce(sy, red);
        float ws = sw + EPSF;
        float cx = sx / ws, cy = sy / ws;
        float smd = 0.f;
        for (int i = t; i < NPV; i += 256) {
            float w = set ? sW2[i] : w1g[i];
            float dx = PX(i) - cx, dy = PY(i) - cy;
            smd += w * (dx * dx + dy * dy);
        }
        smd = block_reduce(smd, red);
        float md = sqrtf(smd / ws + EPSF);
        float sH = 1.4142135623730951f / (md + EPSF);
        if (t == 0) { sPar[set * 3 + 0] = cx; sPar[set * 3 + 1] = cy; sPar[set * 3 + 2] = sH; }
        __syncthreads();
    }

    float c1x = sPar[0], c1y = sPar[1], s1 = sPar[2];
    float c2x = sPar[3], c2y = sPar[4], s2 = sPar[5];

    // Mmat = sum over nonzero (i,j,w) of w * (f1 (x) f2)(f1 (x) f2)^T  (45 unique entries)
    float acc[45];
    #pragma unroll
    for (int k = 0; k < 45; ++k) acc[k] = 0.f;
    for (int i = t; i < NPV; i += 256) {
        int n = rowcnt[i];
        if (n == 0) continue;
        float f1[3];
        f1[0] = (PX(i) - c1x) * s1;
        f1[1] = (PY(i) - c1y) * s1;
        f1[2] = 1.f;
        for (int e = 0; e < n; ++e) {
            int j = rowj[i * 8 + e];
            float w = roww[i * 8 + e];
            float f2[3];
            f2[0] = (PX(j) - c2x) * s2;
            f2[1] = (PY(j) - c2y) * s2;
            f2[2] = 1.f;
            float a[9];
            #pragma unroll
            for (int u = 0; u < 3; ++u)
                #pragma unroll
                for (int v = 0; v < 3; ++v) a[u * 3 + v] = f1[u] * f2[v];
            int idx = 0;
            #pragma unroll
            for (int u = 0; u < 9; ++u) {
                float wa = w * a[u];
                #pragma unroll
                for (int v = u; v < 9; ++v) { acc[idx] = fmaf(wa, a[v], acc[idx]); ++idx; }
            }
        }
    }
    int lane = t & 63, wid = t >> 6;
    #pragma unroll
    for (int k = 0; k < 45; ++k) {
        float v = acc[k];
        v += __shfl_down(v, 32);
        v += __shfl_down(v, 16);
        v += __shfl_down(v, 8);
        v += __shfl_down(v, 4);
        v += __shfl_down(v, 2);
        v += __shfl_down(v, 1);
        if (lane == 0) sMred[wid * 45 + k] = v;
    }
    __syncthreads();
    if (t == 0) {
        float M[81];
        int idx = 0;
        for (int u = 0; u < 9; ++u)
            for (int v = u; v < 9; ++v) {
                float s = sMred[idx] + sMred[45 + idx] + sMred[90 + idx] + sMred[135 + idx];
                M[u * 9 + v] = s; M[v * 9 + u] = s;
                ++idx;
            }
        float lam = 0.f;
        for (int d = 0; d < 9; ++d) lam += M[d * 9 + d];
        for (int r = 0; r < 9; ++r)
            for (int c = 0; c < 9; ++c)
                sMs[r * 9 + c] = (r == c ? lam : 0.f) - M[r * 9 + c];
    }
    __syncthreads();

    // 50-iteration power method on 9x9, wave-parallel: lane r owns row r.
    if (t < 64) {
        float mrow[9];
        #pragma unroll
        for (int c = 0; c < 9; ++c) mrow[c] = (t < 9) ? sMs[t * 9 + c] : 0.f;
        float v = (t < 9) ? (1.f / 3.f) : 0.f;
        for (int it = 0; it < 50; ++it) {
            float y = 0.f;
            #pragma unroll
            for (int c = 0; c < 9; ++c) y = fmaf(mrow[c], __shfl(v, c, 64), y);
            float q = (t < 9) ? y * y : 0.f;
            q += __shfl_xor(q, 1);
            q += __shfl_xor(q, 2);
            q += __shfl_xor(q, 4);
            q += __shfl_xor(q, 8);
            float n = sqrtf(q) + EPSF;
            v = y / n;
        }
        if (t < 9) sV9[t] = v;
    }
    __syncthreads();

    if (t == 0) {
        float Er[9];
        for (int k = 0; k < 9; ++k) Er[k] = sV9[k];
        float T1[9]  = { s1, 0.f, -s1 * c1x,   0.f, s1, -s1 * c1y,   0.f, 0.f, 1.f };
        float T2t[9] = { s2, 0.f, 0.f,   0.f, s2, 0.f,   -s2 * c2x, -s2 * c2y, 1.f };
        float M1[9], E[9];
        mat3mul(Er, T1, M1);
        mat3mul(T2t, M1, E);

        // ---- _project_E ----
        float B[9];
        for (int r = 0; r < 3; ++r)
            for (int c = 0; c < 3; ++c)
                B[r * 3 + c] = E[r] * E[c] + E[3 + r] * E[3 + c] + E[6 + r] * E[6 + c];
        float lam3 = B[0] + B[4] + B[8];
        float v1[3], v3[3], v2[3];
        powiter3(B, v1);
        float Bs[9];
        for (int k = 0; k < 9; ++k) Bs[k] = -B[k];
        Bs[0] += lam3; Bs[4] += lam3; Bs[8] += lam3;
        powiter3(Bs, v3);
        v2[0] = v3[1] * v1[2] - v3[2] * v1[1];
        v2[1] = v3[2] * v1[0] - v3[0] * v1[2];
        v2[2] = v3[0] * v1[1] - v3[1] * v1[0];
        float n2 = sqrtf(v2[0] * v2[0] + v2[1] * v2[1] + v2[2] * v2[2]) + EPSF;
        v2[0] /= n2; v2[1] /= n2; v2[2] /= n2;
        float V[9];
        for (int r = 0; r < 3; ++r) { V[r * 3 + 0] = v1[r]; V[r * 3 + 1] = v2[r]; V[r * 3 + 2] = v3[r]; }
        float dV = det3(V);
        float sV = (dV > 0.f) ? 1.f : ((dV < 0.f) ? -1.f : 0.f);
        V[2] *= sV; V[5] *= sV; V[8] *= sV;
        float Ev1[3], Ev2[3];
        for (int r = 0; r < 3; ++r) {
            Ev1[r] = E[r * 3] * V[0] + E[r * 3 + 1] * V[3] + E[r * 3 + 2] * V[6];
            Ev2[r] = E[r * 3] * V[1] + E[r * 3 + 1] * V[4] + E[r * 3 + 2] * V[7];
        }
        float s1n = sqrtf(Ev1[0] * Ev1[0] + Ev1[1] * Ev1[1] + Ev1[2] * Ev1[2]);
        float s2n = sqrtf(Ev2[0] * Ev2[0] + Ev2[1] * Ev2[1] + Ev2[2] * Ev2[2]);
        float s_avg = (s1n + s2n) * 0.5f;
        float u1[3], u2[3];
        for (int r = 0; r < 3; ++r) { u1[r] = Ev1[r] / (s1n + EPSF); u2[r] = Ev2[r] / (s2n + EPSF); }
        // out = s_avg * (u1 v1^T + u2 v2^T)  (third singular value zeroed; U/V sign flips hit only the zeroed column)
        for (int r = 0; r < 3; ++r)
            for (int c = 0; c < 3; ++c)
                out[r * 3 + c] = s_avg * (u1[r] * V[c * 3 + 0] + u2[r] * V[c * 3 + 1]);
    }
}

extern "C" void kernel_launch(void* const* d_in, const int* in_sizes, int n_in,
                              void* d_out, int out_size, void* d_ws, size_t ws_size,
                              hipStream_t stream)
{
    const float* P = (const float*)d_in[0];
    const float* K = (const float*)d_in[1];
    float* out = (float*)d_out;

    float* fws    = (float*)d_ws;
    float* tr     = fws;                              // 3072
    float* tc     = tr + NPV;                         // 3072
    float* part   = tc + NPV;                         // NSEG*3072*3 = 147456
    float* roww   = part + (size_t)NSEG * NPV * 3;    // 3072*8
    float* w1     = roww + NPV * 8;                   // 3072
    int*   rowj   = (int*)(w1 + NPV);                 // 3072*8
    int*   rowcnt = rowj + NPV * 8;                   // 3072
    // total ~836 KB of d_ws

    k_row_top3<<<NPV, 256, 0, stream>>>(P, tr);
    dim3 g2(NPV / 256, NSEG);
    k_col_top3_part<<<g2, 256, 0, stream>>>(P, part);
    k_col_merge<<<NPV / 256, 256, 0, stream>>>(part, tc);
    k_collect<<<NPV, 256, 0, stream>>>(P, tr, tc, rowcnt, rowj, roww, w1);
    k_final<<<1, 256, 0, stream>>>(K, rowcnt, rowj, roww, w1, out);
}